// Round 5
// baseline (448.585 us; speedup 1.0000x reference)
//
#include <hip/hip_runtime.h>
#include <hip/hip_bf16.h>
#include <math.h>

// Problem constants
#define NN   2048
#define EE   32768
#define NS   32
#define NV   16
#define NB   8          // NUM_BASIS
#define DD   32
#define TT   32
#define LL   2
#define HRD  64
#define NWW  3072
#define PI_F 3.14159265358979323846f

// scales
#define SC_SCS (1.0f/32.0f)                 // 1/sqrt(NS*D)
#define SC_SCV 0.04419417382415922f         // 1/sqrt(NV*D)=1/sqrt(512)
#define SC_L1S 0.17677669529663687f         // 1/sqrt(32)
#define SC_L1V 0.25f                        // 1/sqrt(16)
#define SC_R1  0.25f                        // 1/sqrt(2B)
#define SC_R2  0.125f                       // 1/sqrt(HR)
#define SC_ES  0.10206207261596575f         // 1/sqrt(96)
#define SC_EV  0.125f                       // 1/sqrt(64)
#define SC_AGG 0.25f                        // 1/sqrt(16)
#define SC_L2S 0.14433756729740643f         // 1/sqrt(48)
#define SC_L2V 0.25f
#define SC_SIS 0.17677669529663687f
#define SC_SIV 0.25f

typedef __attribute__((ext_vector_type(8))) short  short8;   // 8 bf16 (4 VGPRs)
typedef __attribute__((ext_vector_type(4))) float  floatx4;  // MFMA C/D

// ------------------------------------------------------------- K_setup
__global__ void k_setup(const float* __restrict__ Wup, float* __restrict__ Q,
                        const float* __restrict__ emb,
                        const float* __restrict__ Wscs, const float* __restrict__ Wscv,
                        float* __restrict__ WtS, float* __restrict__ WtV,
                        const float* __restrict__ Wr2, __hip_bfloat16* __restrict__ wr2t,
                        int* __restrict__ deg, int* __restrict__ cursor) {
    int b = blockIdx.x;
    if (b == 0) {
        if (threadIdx.x != 0) return;
        double A[16][2], tau[2];
        for (int i = 0; i < 16; ++i)
            for (int j = 0; j < 2; ++j) A[i][j] = (double)Wup[i*2 + j];
        for (int j = 0; j < 2; ++j) {
            double alpha = A[j][j];
            double xn2 = 0.0;
            for (int i = j + 1; i < 16; ++i) xn2 += A[i][j]*A[i][j];
            if (xn2 == 0.0) {
                tau[j] = 0.0;
            } else {
                double nrm  = sqrt(alpha*alpha + xn2);
                double beta = (alpha >= 0.0) ? -nrm : nrm;
                tau[j] = (beta - alpha) / beta;
                double s = 1.0 / (alpha - beta);
                for (int i = j + 1; i < 16; ++i) A[i][j] *= s;
                A[j][j] = beta;
            }
            for (int k = j + 1; k < 2; ++k) {
                double w = A[j][k];
                for (int i = j + 1; i < 16; ++i) w += A[i][j]*A[i][k];
                w *= tau[j];
                A[j][k] -= w;
                for (int i = j + 1; i < 16; ++i) A[i][k] -= A[i][j]*w;
            }
        }
        double Qm[16][2];
        for (int i = 0; i < 16; ++i)
            for (int j = 0; j < 2; ++j) Qm[i][j] = (i == j) ? 1.0 : 0.0;
        for (int j = 1; j >= 0; --j) {
            for (int k = 0; k < 2; ++k) {
                double w = Qm[j][k];
                for (int i = j + 1; i < 16; ++i) w += A[i][j]*Qm[i][k];
                w *= tau[j];
                Qm[j][k] -= w;
                for (int i = j + 1; i < 16; ++i) Qm[i][k] -= A[i][j]*w;
            }
        }
        for (int i = 0; i < 16; ++i)
            for (int j = 0; j < 2; ++j) Q[i*2 + j] = (float)Qm[i][j];
    } else if (b <= 64) {
        int lt = b - 1;
        int l = lt >> 5, t = lt & 31;
        __shared__ float es[32];
        if (threadIdx.x < 32) es[threadIdx.x] = emb[t*DD + threadIdx.x];
        __syncthreads();
        const float* Ws = Wscs + (size_t)l*NS*DD*48;
        float* oS = WtS + (size_t)(l*TT + t)*NS*48;
        for (int idx = threadIdx.x; idx < NS*48; idx += 256) {
            int i = idx / 48, j = idx % 48;
            float acc = 0.f;
            for (int a = 0; a < 32; ++a) acc += es[a]*Ws[(i*DD + a)*48 + j];
            oS[idx] = acc;
        }
        const float* Wv = Wscv + (size_t)l*NV*DD*NV;
        float* oV = WtV + (size_t)(l*TT + t)*NV*NV;
        for (int idx = threadIdx.x; idx < NV*NV; idx += 256) {
            int c = idx / 16, j = idx % 16;
            float acc = 0.f;
            for (int a = 0; a < 32; ++a) acc += es[a]*Wv[(c*DD + a)*NV + j];
            oV[idx] = acc;
        }
    } else if (b <= 1600) {
        int idx = (b - 65)*256 + threadIdx.x;      // L*64*3072 total
        int l = idx / (HRD*NWW);
        int r = idx - l*(HRD*NWW);
        int k = r / NWW;
        int c = r - k*NWW;
        wr2t[((size_t)l*NWW + c)*HRD + k] = __float2bfloat16(Wr2[idx]);
    } else {
        int i = (b - 1601)*256 + threadIdx.x;
        if (i < NN) { deg[i] = 0; cursor[i] = 0; }
    }
}

// --------------------------------------------------------------- CSR build
__global__ void k_hist(const int* __restrict__ edst, int* __restrict__ deg) {
    int e = blockIdx.x*256 + threadIdx.x;
    atomicAdd(&deg[edst[e]], 1);
}

__global__ void k_scan(const int* __restrict__ deg, int* __restrict__ row_ptr) {
    __shared__ int part[256];
    __shared__ int psc[256];
    int t = threadIdx.x;
    int loc[8]; int s = 0;
    for (int k = 0; k < 8; ++k) { loc[k] = deg[t*8 + k]; s += loc[k]; }
    part[t] = s;
    __syncthreads();
    if (t == 0) { int run = 0; for (int i = 0; i < 256; ++i) { psc[i] = run; run += part[i]; } }
    __syncthreads();
    int off = psc[t];
    for (int k = 0; k < 8; ++k) { row_ptr[t*8 + k] = off; off += loc[k]; }
    if (t == 255) row_ptr[2048] = off;
}

// blocks 0..127: fill invperm + pre-permuted src/dst; blocks 128..135: init y
__global__ void k_fill(const int* __restrict__ esrc, const int* __restrict__ edst,
                       const int* __restrict__ row_ptr, int* __restrict__ cursor,
                       int* __restrict__ invperm, int* __restrict__ srcs, int* __restrict__ dsts,
                       const float* __restrict__ xin, const float* __restrict__ Q,
                       float* __restrict__ ys0, float* __restrict__ yv0,
                       float* __restrict__ ys1, float* __restrict__ yv1,
                       float* __restrict__ xcur) {
    if (blockIdx.x < 128) {
        int e = blockIdx.x*256 + threadIdx.x;
        int d = edst[e];
        int pos = atomicAdd(&cursor[d], 1);
        int p = row_ptr[d] + pos;
        invperm[e] = p;
        srcs[p] = esrc[e];
        dsts[p] = d;
    } else {
        int n = (blockIdx.x - 128)*256 + threadIdx.x;  // exactly 2048
        float xl[6];
        for (int i = 0; i < 6; ++i) { xl[i] = xin[n*6 + i]; xcur[n*6 + i] = xl[i]; }
        for (int j = 0; j < 32; ++j) { ys0[n*32 + j] = 0.f; ys1[n*32 + j] = 0.f; }
        for (int c = 0; c < 16; ++c)
            for (int k = 0; k < 3; ++k) {
                float v = Q[c*2 + 0]*xl[k] + Q[c*2 + 1]*xl[3 + k];
                yv0[n*48 + c*3 + k] = v;
                yv1[n*48 + c*3 + k] = v;
            }
    }
}

// -------------------- K_pre: blocks 0..127 edge geometry+radial1 (permuted
// write), blocks 128..511 node lin1 + aggregator zeroing
__global__ void __launch_bounds__(256) k_pre(
        const float* __restrict__ xcur,
        const int* __restrict__ esrc, const int* __restrict__ edst,
        const int* __restrict__ invperm,
        const float* __restrict__ Wr1l,
        __hip_bfloat16* __restrict__ hrg, float* __restrict__ eag,
        const float* __restrict__ ys, const float* __restrict__ yv,
        const float* __restrict__ Wl1s, const float* __restrict__ Wl1v,
        float* __restrict__ s1, float* __restrict__ v1,
        float* __restrict__ nsb, float* __restrict__ nvba, float* __restrict__ nvbb) {
    if (blockIdx.x < 128) {
        __shared__ float Wr1[16*64];
        for (int i = threadIdx.x; i < 16*64; i += 256) Wr1[i] = Wr1l[i];
        __syncthreads();
        int e = blockIdx.x*256 + threadIdx.x;
        int s = esrc[e], d = edst[e];
        int p = invperm[e];
        float ef[16];
        for (int m = 0; m < 2; ++m) {
            float v0 = xcur[s*6 + m*3 + 0] - xcur[d*6 + m*3 + 0];
            float v1_ = xcur[s*6 + m*3 + 1] - xcur[d*6 + m*3 + 1];
            float v2 = xcur[s*6 + m*3 + 2] - xcur[d*6 + m*3 + 2];
            float len = sqrtf(v0*v0 + v1_*v1_ + v2*v2 + 1e-12f);
            float inv = 1.0f/len;
            float theta = len*(PI_F/3.0f);
            float s1v = sinf(theta), c1v = cosf(theta);
            float sc  = 2.3094010767585034f*inv;  // sqrt(2/3)*sqrt(8)
            float sp = 0.f, scur = s1v, twoc = 2.f*c1v;
            for (int bq = 0; bq < 8; ++bq) {
                ef[m*8 + bq] = sc*scur;
                float sn = twoc*scur - sp;
                sp = scur; scur = sn;
            }
            float u = 2.0f*(len*(1.0f/3.0f) - 1.0f);
            float cut;
            if (u > 0.f) cut = 0.f;
            else if (u < -1.f) cut = 1.f;
            else cut = 0.5f*(1.0f - cosf(PI_F*u));
            float shs = 1.7320508075688772f*inv*cut;
            eag[p*6 + m*3 + 0] = shs*v0;
            eag[p*6 + m*3 + 1] = shs*v1_;
            eag[p*6 + m*3 + 2] = shs*v2;
        }
        for (int hh = 0; hh < 64; ++hh) {
            float z = 0.f;
            for (int f = 0; f < 16; ++f) z += ef[f]*Wr1[f*64 + hh];
            z *= SC_R1;
            hrg[(size_t)p*64 + hh] = __float2bfloat16(z/(1.0f + expf(-z)));
        }
    } else {
        int idx = (blockIdx.x - 128)*256 + threadIdx.x;  // exactly 2048*48
        int n = idx / 48, r = idx % 48;
        nsb[idx] = 0.f;
        nvba[idx] = 0.f;
        nvbb[idx] = 0.f;
        if (r < 32) {
            float acc = 0.f;
            for (int i = 0; i < 32; ++i) acc += ys[n*32 + i]*Wl1s[i*32 + r];
            s1[n*32 + r] = acc*SC_L1S;
        }
        int j = r/3, k = r - 3*j;
        float acc = 0.f;
        for (int c = 0; c < 16; ++c) acc += yv[n*48 + c*3 + k]*Wl1v[c*16 + j];
        v1[idx] = acc*SC_L1V;
    }
}

// ------------------------------ K_tp: fused radial2-MFMA + edge TP + reduce
// 3 region-blocks per 64-edge tile (blockIdx%3: 0=sv,1=vs,2=vv) -> grid 1536,
// 6 blocks/CU resident (24 waves/CU) instead of 2 (8 waves). Regions write
// disjoint buffers (nsb / nvb_a / nvb_b) so the exclusive-store optimization
// survives the split; k_nodepost sums nvb_a+nvb_b.
__global__ void __launch_bounds__(256) k_tp(
        const __hip_bfloat16* __restrict__ hrg, const float* __restrict__ eag,
        const float* __restrict__ s1g, const float* __restrict__ v1g,
        const int* __restrict__ srcs, const int* __restrict__ dsts,
        const int* __restrict__ row_ptr,
        const __hip_bfloat16* __restrict__ wr2tl,
        float* __restrict__ nsb, float* __restrict__ nvba, float* __restrict__ nvbb) {
    __shared__ __align__(16) char smem[21760];
    __shared__ float ea_s[64][8];
    __shared__ int   src_s[64];
    __shared__ int   dst_s[64];

    int bid = blockIdx.x;
    int region = bid % 3;
    int tile   = bid / 3;
    int ebase  = tile*64;
    int tid = threadIdx.x;
    int wave = tid >> 6, lane = tid & 63;
    int te = tid >> 4, tc = tid & 15;
    int quad = lane >> 4;
    int e0 = 4*te;   // == wave*16 + quad*4

    if (tid < 64) { src_s[tid] = srcs[ebase + tid]; dst_s[tid] = dsts[ebase + tid]; }
    for (int i = tid; i < 64*6; i += 256) ea_s[i/6][i%6] = eag[(size_t)ebase*6 + i];
    __syncthreads();

    // A fragments (chunk-invariant): lane holds hr[arow][quad*8 + j]
    const short* hr16 = (const short*)hrg;
    const short* w16  = (const short*)wr2tl;
    int arow = ebase + wave*16 + (lane & 15);
    short8 a_lo = *(const short8*)(hr16 + (size_t)arow*64 + quad*8);
    short8 a_hi = *(const short8*)(hr16 + (size_t)arow*64 + 32 + quad*8);

    const float sES = SC_R2*SC_ES*SC_AGG;
    const float sEV = SC_R2*SC_EV*SC_AGG;

    if (region == 0) {
        // ---------------- sv: ch 0..15 -> accEV -> nvb_a
        float (*s1t)[68] = (float(*)[68])smem;                 // 8704 B
        for (int i = tid; i < 64*32; i += 256) {
            int e = i >> 5, s = i & 31;
            s1t[s][e] = s1g[src_s[e]*32 + s];
        }
        float ear[4][6];
        #pragma unroll
        for (int i = 0; i < 4; ++i)
            #pragma unroll
            for (int k = 0; k < 6; ++k) ear[i][k] = ea_s[e0 + i][k];
        __syncthreads();

        float accEV[4][3] = {{0,0,0},{0,0,0},{0,0,0},{0,0,0}};
        #pragma unroll 2
        for (int ch = 0; ch < 16; ++ch) {
            #pragma unroll
            for (int q = 0; q < 4; ++q) {
                int col = ch*64 + q*16 + tc;
                const short* bp = w16 + (size_t)col*64 + quad*8;
                short8 b_lo = *(const short8*)(bp);
                short8 b_hi = *(const short8*)(bp + 32);
                floatx4 c = {0.f, 0.f, 0.f, 0.f};
                c = __builtin_amdgcn_mfma_f32_16x16x32_bf16(a_lo, b_lo, c, 0, 0, 0);
                c = __builtin_amdgcn_mfma_f32_16x16x32_bf16(a_hi, b_hi, c, 0, 0, 0);
                int m = q & 1;
                float4 sv = *(const float4*)&s1t[ch*2 + (q >> 1)][e0];
                #pragma unroll
                for (int i = 0; i < 4; ++i) {
                    float f = c[i]*((&sv.x)[i]);
                    accEV[i][0] += f*ear[i][m*3 + 0];
                    accEV[i][1] += f*ear[i][m*3 + 1];
                    accEV[i][2] += f*ear[i][m*3 + 2];
                }
            }
        }
        __syncthreads();   // all s1t reads done
        float (*red)[49] = (float(*)[49])smem;                 // 12544 B (aliases s1t)
        #pragma unroll
        for (int i = 0; i < 4; ++i) {
            int pos = e0 + i;
            red[pos][tc*3 + 0] = accEV[i][0]*sEV;
            red[pos][tc*3 + 1] = accEV[i][1]*sEV;
            red[pos][tc*3 + 2] = accEV[i][2]*sEV;
        }
        __syncthreads();
        if (tid < 48) {
            int c = tid;
            float run = 0.f;
            int cur = dst_s[0];
            for (int pos = 0; pos < 64; ++pos) {
                int d = dst_s[pos];
                if (d != cur) {
                    if (row_ptr[cur] >= ebase && row_ptr[cur + 1] <= ebase + 64)
                        nvba[cur*48 + c] = run;
                    else
                        atomicAdd(&nvba[cur*48 + c], run);
                    run = 0.f; cur = d;
                }
                run += red[pos][c];
            }
            if (row_ptr[cur] >= ebase && row_ptr[cur + 1] <= ebase + 64)
                nvba[cur*48 + c] = run;
            else
                atomicAdd(&nvba[cur*48 + c], run);
        }
    } else if (region == 1) {
        // ---------------- vs: ch 16..39 -> accES -> nsb
        float (*dots_t)[68] = (float(*)[68])smem;              //  8704 B
        float (*v1t)[68]    = (float(*)[68])(smem + 8704);     // 13056 B
        for (int i = tid; i < 64*48; i += 256) {
            int e = i/48, j = i%48;
            v1t[j][e] = v1g[src_s[e]*48 + j];
        }
        __syncthreads();
        for (int i = tid; i < 64*32; i += 256) {
            int cm = i >> 6, e = i & 63, c = cm >> 1, m = cm & 1;
            dots_t[cm][e] = v1t[c*3+0][e]*ea_s[e][m*3+0]
                          + v1t[c*3+1][e]*ea_s[e][m*3+1]
                          + v1t[c*3+2][e]*ea_s[e][m*3+2];
        }
        __syncthreads();

        float accES[4][3] = {{0,0,0},{0,0,0},{0,0,0},{0,0,0}};
        #pragma unroll 2
        for (int ch = 16; ch < 40; ++ch) {
            #pragma unroll
            for (int q = 0; q < 4; ++q) {
                int col = ch*64 + q*16 + tc;
                const short* bp = w16 + (size_t)col*64 + quad*8;
                short8 b_lo = *(const short8*)(bp);
                short8 b_hi = *(const short8*)(bp + 32);
                floatx4 c4 = {0.f, 0.f, 0.f, 0.f};
                c4 = __builtin_amdgcn_mfma_f32_16x16x32_bf16(a_lo, b_lo, c4, 0, 0, 0);
                c4 = __builtin_amdgcn_mfma_f32_16x16x32_bf16(a_hi, b_hi, c4, 0, 0, 0);
                int u = ch*4 + q - 64;           // [0,96)
                int c = (u*10923) >> 16;         // u/6
                int v6 = u - 6*c;
                int m = (v6 >= 3) ? 1 : 0;
                int g = v6 - 3*m;
                float4 dv = *(const float4*)&dots_t[c*2 + m][e0];
                #pragma unroll
                for (int i = 0; i < 4; ++i)
                    accES[i][g] += c4[i]*((&dv.x)[i]);
            }
        }
        __syncthreads();   // all dots reads done
        float (*red)[49] = (float(*)[49])(smem + 8704);        // aliases v1t
        #pragma unroll
        for (int i = 0; i < 4; ++i) {
            int pos = e0 + i;
            red[pos][tc]      = accES[i][0]*sES;
            red[pos][16 + tc] = accES[i][1]*sES;
            red[pos][32 + tc] = accES[i][2]*sES;
        }
        __syncthreads();
        if (tid < 48) {
            int c = tid;
            float run = 0.f;
            int cur = dst_s[0];
            for (int pos = 0; pos < 64; ++pos) {
                int d = dst_s[pos];
                if (d != cur) {
                    if (row_ptr[cur] >= ebase && row_ptr[cur + 1] <= ebase + 64)
                        nsb[cur*48 + c] = run;
                    else
                        atomicAdd(&nsb[cur*48 + c], run);
                    run = 0.f; cur = d;
                }
                run += red[pos][c];
            }
            if (row_ptr[cur] >= ebase && row_ptr[cur + 1] <= ebase + 64)
                nsb[cur*48 + c] = run;
            else
                atomicAdd(&nsb[cur*48 + c], run);
        }
    } else {
        // ---------------- vv: ch 40..47 -> accEV (cross) -> nvb_b
        float (*v1t)[68] = (float(*)[68])smem;                 // 13056 B
        for (int i = tid; i < 64*48; i += 256) {
            int e = i/48, j = i%48;
            v1t[j][e] = v1g[src_s[e]*48 + j];
        }
        float ear[4][6];
        #pragma unroll
        for (int i = 0; i < 4; ++i)
            #pragma unroll
            for (int k = 0; k < 6; ++k) ear[i][k] = ea_s[e0 + i][k];
        __syncthreads();

        float accEV[4][3] = {{0,0,0},{0,0,0},{0,0,0},{0,0,0}};
        #pragma unroll 2
        for (int ch = 40; ch < 48; ++ch) {
            #pragma unroll
            for (int q = 0; q < 4; ++q) {
                int col = ch*64 + q*16 + tc;
                const short* bp = w16 + (size_t)col*64 + quad*8;
                short8 b_lo = *(const short8*)(bp);
                short8 b_hi = *(const short8*)(bp + 32);
                floatx4 c4 = {0.f, 0.f, 0.f, 0.f};
                c4 = __builtin_amdgcn_mfma_f32_16x16x32_bf16(a_lo, b_lo, c4, 0, 0, 0);
                c4 = __builtin_amdgcn_mfma_f32_16x16x32_bf16(a_hi, b_hi, c4, 0, 0, 0);
                int c = ch*2 - 80 + (q >> 1);
                int m = q & 1;
                float4 vx = *(const float4*)&v1t[c*3 + 0][e0];
                float4 vy = *(const float4*)&v1t[c*3 + 1][e0];
                float4 vz = *(const float4*)&v1t[c*3 + 2][e0];
                #pragma unroll
                for (int i = 0; i < 4; ++i) {
                    float ww = c4[i];
                    float a0 = ear[i][m*3 + 0], a1 = ear[i][m*3 + 1], a2 = ear[i][m*3 + 2];
                    float xv = (&vx.x)[i], yv = (&vy.x)[i], zv = (&vz.x)[i];
                    accEV[i][0] += ww*(yv*a2 - zv*a1);
                    accEV[i][1] += ww*(zv*a0 - xv*a2);
                    accEV[i][2] += ww*(xv*a1 - yv*a0);
                }
            }
        }
        __syncthreads();   // all v1t reads done
        float (*red)[49] = (float(*)[49])smem;                 // aliases v1t
        #pragma unroll
        for (int i = 0; i < 4; ++i) {
            int pos = e0 + i;
            red[pos][tc*3 + 0] = accEV[i][0]*sEV;
            red[pos][tc*3 + 1] = accEV[i][1]*sEV;
            red[pos][tc*3 + 2] = accEV[i][2]*sEV;
        }
        __syncthreads();
        if (tid < 48) {
            int c = tid;
            float run = 0.f;
            int cur = dst_s[0];
            for (int pos = 0; pos < 64; ++pos) {
                int d = dst_s[pos];
                if (d != cur) {
                    if (row_ptr[cur] >= ebase && row_ptr[cur + 1] <= ebase + 64)
                        nvbb[cur*48 + c] = run;
                    else
                        atomicAdd(&nvbb[cur*48 + c], run);
                    run = 0.f; cur = d;
                }
                run += red[pos][c];
            }
            if (row_ptr[cur] >= ebase && row_ptr[cur + 1] <= ebase + 64)
                nvbb[cur*48 + c] = run;
            else
                atomicAdd(&nvbb[cur*48 + c], run);
        }
    }
}

// ----------------------- K6: node update (conv, gate, si, leapfrog, project)
__global__ void __launch_bounds__(256) k_nodepost(
        const float* __restrict__ ysC, const float* __restrict__ yvC,
        float* __restrict__ ysO, float* __restrict__ yvO,
        const float* __restrict__ nsb, const float* __restrict__ nvba,
        const float* __restrict__ nvbb,
        const int* __restrict__ nattr,
        const float* __restrict__ WtSl, const float* __restrict__ WtVl,
        const float* __restrict__ Wl2s, const float* __restrict__ Wl2v,
        const float* __restrict__ Wsis, const float* __restrict__ Wsiv,
        const float* __restrict__ harr, const float* __restrict__ mixarr, int l,
        float* __restrict__ xcur, float* __restrict__ xout2,
        const float* __restrict__ Qg) {
    int wave = threadIdx.x >> 6, lane = threadIdx.x & 63;
    int n = blockIdx.x*4 + wave;
    __shared__ float ys_s[4][32], yv_s[4][48], ns_s[4][48], nv_s[4][48];
    __shared__ float cs_s[4][48], nvo_s[4][48];

    if (lane < 32) ys_s[wave][lane] = ysC[n*32 + lane];
    if (lane < 48) {
        yv_s[wave][lane] = yvC[n*48 + lane];
        ns_s[wave][lane] = nsb[n*48 + lane];
        nv_s[wave][lane] = nvba[n*48 + lane] + nvbb[n*48 + lane];
    }
    __syncthreads();
    int t = nattr[n];
    const float* WtSn = WtSl + (size_t)t*NS*48;
    const float* WtVn = WtVl + (size_t)t*NV*NV;
    float hv = harr[l];
    float h2 = hv*hv, mx = mixarr[l];

    if (lane < 48) {
        float sc = 0.f, s2 = 0.f;
        for (int i = 0; i < 32; ++i) sc += ys_s[wave][i]*WtSn[i*48 + lane];
        for (int c = 0; c < 48; ++c) s2 += ns_s[wave][c]*Wl2s[c*48 + lane];
        cs_s[wave][lane] = sc*SC_SCS + s2*SC_L2S;
    }
    __syncthreads();
    if (lane < 48) {
        int j = lane/3, k = lane - 3*j;
        float scv = 0.f, v2 = 0.f, siv = 0.f;
        for (int c = 0; c < 16; ++c) {
            float yvv = yv_s[wave][c*3 + k];
            scv += yvv*WtVn[c*16 + j];
            v2  += nv_s[wave][c*3 + k]*Wl2v[c*16 + j];
            siv += yvv*Wsiv[c*16 + j];
        }
        float convv = scv*SC_SCV + v2*SC_L2V;
        siv *= SC_SIV;
        float gate = 1.f/(1.f + expf(-cs_s[wave][32 + j]));
        float gv = gate*convv;
        float nvnew = 2.f*yv_s[wave][lane] - yvO[n*48 + lane] + h2*(mx*gv + (mx - 1.f)*siv);
        nvo_s[wave][lane] = nvnew;
        yvO[n*48 + lane] = nvnew;
    }
    if (lane < 32) {
        float sis = 0.f;
        for (int i = 0; i < 32; ++i) sis += ys_s[wave][i]*Wsis[i*32 + lane];
        sis *= SC_SIS;
        float cs = cs_s[wave][lane];
        float gs = cs/(1.f + expf(-cs));
        float nsnew = 2.f*ys_s[wave][lane] - ysO[n*32 + lane] + h2*(mx*gs + (mx - 1.f)*sis);
        ysO[n*32 + lane] = nsnew;
    }
    __syncthreads();
    if (lane < 6) {
        int i = lane/3, k = lane - 3*(lane/3);
        float acc = 0.f;
        for (int c = 0; c < 16; ++c) acc += Qg[c*2 + i]*nvo_s[wave][c*3 + k];
        xcur[n*6 + lane]  = acc;
        xout2[n*6 + lane] = acc;
    }
}

// ---------------------------------------------------------------- launch
extern "C" void kernel_launch(void* const* d_in, const int* in_sizes, int n_in,
                              void* d_out, int out_size, void* d_ws, size_t ws_size,
                              hipStream_t stream) {
    const float* x_in  = (const float*)d_in[0];
    const int*   nattr = (const int*)  d_in[2];
    const int*   esrc  = (const int*)  d_in[3];
    const int*   edst  = (const int*)  d_in[4];
    const float* emb   = (const float*)d_in[5];
    const float* Wup   = (const float*)d_in[6];
    const float* Wscs  = (const float*)d_in[7];
    const float* Wscv  = (const float*)d_in[8];
    const float* Wl1s  = (const float*)d_in[9];
    const float* Wl1v  = (const float*)d_in[10];
    const float* Wr1   = (const float*)d_in[11];
    const float* Wr2   = (const float*)d_in[12];
    const float* Wl2s  = (const float*)d_in[13];
    const float* Wl2v  = (const float*)d_in[14];
    const float* Wsis  = (const float*)d_in[15];
    const float* Wsiv  = (const float*)d_in[16];
    const float* harr  = (const float*)d_in[17];
    const float* mixar = (const float*)d_in[18];
    float* out = (float*)d_out;

    float* ws = (float*)d_ws;
    size_t off = 0;
    float* Q    = ws + off; off += 32;
    float* WtS  = ws + off; off += (size_t)LL*TT*NS*48;     // 98304
    float* WtV  = ws + off; off += (size_t)LL*TT*NV*NV;     // 16384
    float* ys0  = ws + off; off += (size_t)NN*32;
    float* yv0  = ws + off; off += (size_t)NN*48;
    float* ys1  = ws + off; off += (size_t)NN*32;
    float* yv1  = ws + off; off += (size_t)NN*48;
    float* xcur = ws + off; off += (size_t)NN*6;
    float* s1   = ws + off; off += (size_t)NN*32;
    float* v1   = ws + off; off += (size_t)NN*48;
    float* nsb  = ws + off; off += (size_t)NN*48;
    float* nvba = ws + off; off += (size_t)NN*48;
    float* nvbb = ws + off; off += (size_t)NN*48;
    float* eab  = ws + off; off += (size_t)EE*6;
    off = (off + 3) & ~(size_t)3;                           // 16B align
    __hip_bfloat16* hrb  = (__hip_bfloat16*)(ws + off); off += (size_t)EE*64/2;       // bf16
    __hip_bfloat16* wr2t = (__hip_bfloat16*)(ws + off); off += (size_t)LL*NWW*HRD/2;  // bf16
    int* deg     = (int*)(ws + off); off += NN;
    int* cursor  = (int*)(ws + off); off += NN;
    int* row_ptr = (int*)(ws + off); off += NN + 1;
    int* invperm = (int*)(ws + off); off += EE;
    int* srcs    = (int*)(ws + off); off += EE;
    int* dsts    = (int*)(ws + off); off += EE;

    k_setup<<<1609, 256, 0, stream>>>(Wup, Q, emb, Wscs, Wscv, WtS, WtV, Wr2, wr2t,
                                      deg, cursor);
    k_hist<<<EE/256, 256, 0, stream>>>(edst, deg);
    k_scan<<<1, 256, 0, stream>>>(deg, row_ptr);
    k_fill<<<136, 256, 0, stream>>>(esrc, edst, row_ptr, cursor, invperm, srcs, dsts,
                                    x_in, Q, ys0, yv0, ys1, yv1, xcur);

    float* curS = ys0; float* curV = yv0;
    float* oldS = ys1; float* oldV = yv1;
    for (int l = 0; l < LL; ++l) {
        k_pre<<<512, 256, 0, stream>>>(xcur, esrc, edst, invperm,
                                       Wr1 + (size_t)l*16*64, hrb, eab,
                                       curS, curV, Wl1s + (size_t)l*32*32,
                                       Wl1v + (size_t)l*16*16, s1, v1, nsb, nvba, nvbb);
        k_tp<<<3*EE/64, 256, 0, stream>>>(hrb, eab, s1, v1, srcs, dsts, row_ptr,
                                          wr2t + (size_t)l*NWW*HRD, nsb, nvba, nvbb);
        float* xo2 = (l == LL - 1) ? out : xcur;
        k_nodepost<<<NN/4, 256, 0, stream>>>(curS, curV, oldS, oldV, nsb, nvba, nvbb, nattr,
                                             WtS + (size_t)l*TT*NS*48, WtV + (size_t)l*TT*NV*NV,
                                             Wl2s + (size_t)l*48*48, Wl2v + (size_t)l*16*16,
                                             Wsis + (size_t)l*32*32, Wsiv + (size_t)l*16*16,
                                             harr, mixar, l, xcur, xo2, Q);
        float* ts = curS; curS = oldS; oldS = ts;
        float* tv = curV; curV = oldV; oldV = tv;
    }
}

// Round 6
// 306.386 us; speedup vs baseline: 1.4641x; 1.4641x over previous
//
#include <hip/hip_runtime.h>
#include <hip/hip_bf16.h>
#include <math.h>

// Problem constants
#define NN   2048
#define EE   32768
#define NS   32
#define NV   16
#define NB   8          // NUM_BASIS
#define DD   32
#define TT   32
#define LL   2
#define HRD  64
#define NWW  3072
#define TPE  128        // edges per k_tp tile
#define PI_F 3.14159265358979323846f

// scales
#define SC_SCS (1.0f/32.0f)                 // 1/sqrt(NS*D)
#define SC_SCV 0.04419417382415922f         // 1/sqrt(NV*D)=1/sqrt(512)
#define SC_L1S 0.17677669529663687f         // 1/sqrt(32)
#define SC_L1V 0.25f                        // 1/sqrt(16)
#define SC_R1  0.25f                        // 1/sqrt(2B)
#define SC_R2  0.125f                       // 1/sqrt(HR)
#define SC_ES  0.10206207261596575f         // 1/sqrt(96)
#define SC_EV  0.125f                       // 1/sqrt(64)
#define SC_AGG 0.25f                        // 1/sqrt(16)
#define SC_L2S 0.14433756729740643f         // 1/sqrt(48)
#define SC_L2V 0.25f
#define SC_SIS 0.17677669529663687f
#define SC_SIV 0.25f

typedef __attribute__((ext_vector_type(8))) short  short8;   // 8 bf16 (4 VGPRs)
typedef __attribute__((ext_vector_type(4))) float  floatx4;  // MFMA C/D

__device__ __forceinline__ void load_lds16(const void* g, void* l) {
    __builtin_amdgcn_global_load_lds(
        (const __attribute__((address_space(1))) unsigned int*)g,
        (__attribute__((address_space(3))) unsigned int*)l, 16, 0, 0);
}

__device__ __forceinline__ floatx4 mfma16(short8 a, short8 b, floatx4 c) {
    return __builtin_amdgcn_mfma_f32_16x16x32_bf16(a, b, c, 0, 0, 0);
}

// ------------------------------------------------------------- K_setup
// block 0: Householder QR; 1..64: per-type sc weights; 65..1600: W_r2 ->
// bf16 in MFMA staging order [ch][q][half][quad][tc][8]; 1601+: zero CSR.
__global__ void k_setup(const float* __restrict__ Wup, float* __restrict__ Q,
                        const float* __restrict__ emb,
                        const float* __restrict__ Wscs, const float* __restrict__ Wscv,
                        float* __restrict__ WtS, float* __restrict__ WtV,
                        const float* __restrict__ Wr2, __hip_bfloat16* __restrict__ wr2t,
                        int* __restrict__ deg, int* __restrict__ cursor) {
    int b = blockIdx.x;
    if (b == 0) {
        if (threadIdx.x != 0) return;
        double A[16][2], tau[2];
        for (int i = 0; i < 16; ++i)
            for (int j = 0; j < 2; ++j) A[i][j] = (double)Wup[i*2 + j];
        for (int j = 0; j < 2; ++j) {
            double alpha = A[j][j];
            double xn2 = 0.0;
            for (int i = j + 1; i < 16; ++i) xn2 += A[i][j]*A[i][j];
            if (xn2 == 0.0) {
                tau[j] = 0.0;
            } else {
                double nrm  = sqrt(alpha*alpha + xn2);
                double beta = (alpha >= 0.0) ? -nrm : nrm;
                tau[j] = (beta - alpha) / beta;
                double s = 1.0 / (alpha - beta);
                for (int i = j + 1; i < 16; ++i) A[i][j] *= s;
                A[j][j] = beta;
            }
            for (int k = j + 1; k < 2; ++k) {
                double w = A[j][k];
                for (int i = j + 1; i < 16; ++i) w += A[i][j]*A[i][k];
                w *= tau[j];
                A[j][k] -= w;
                for (int i = j + 1; i < 16; ++i) A[i][k] -= A[i][j]*w;
            }
        }
        double Qm[16][2];
        for (int i = 0; i < 16; ++i)
            for (int j = 0; j < 2; ++j) Qm[i][j] = (i == j) ? 1.0 : 0.0;
        for (int j = 1; j >= 0; --j) {
            for (int k = 0; k < 2; ++k) {
                double w = Qm[j][k];
                for (int i = j + 1; i < 16; ++i) w += A[i][j]*Qm[i][k];
                w *= tau[j];
                Qm[j][k] -= w;
                for (int i = j + 1; i < 16; ++i) Qm[i][k] -= A[i][j]*w;
            }
        }
        for (int i = 0; i < 16; ++i)
            for (int j = 0; j < 2; ++j) Q[i*2 + j] = (float)Qm[i][j];
    } else if (b <= 64) {
        int lt = b - 1;
        int l = lt >> 5, t = lt & 31;
        __shared__ float es[32];
        if (threadIdx.x < 32) es[threadIdx.x] = emb[t*DD + threadIdx.x];
        __syncthreads();
        const float* Ws = Wscs + (size_t)l*NS*DD*48;
        float* oS = WtS + (size_t)(l*TT + t)*NS*48;
        for (int idx = threadIdx.x; idx < NS*48; idx += 256) {
            int i = idx / 48, j = idx % 48;
            float acc = 0.f;
            for (int a = 0; a < 32; ++a) acc += es[a]*Ws[(i*DD + a)*48 + j];
            oS[idx] = acc;
        }
        const float* Wv = Wscv + (size_t)l*NV*DD*NV;
        float* oV = WtV + (size_t)(l*TT + t)*NV*NV;
        for (int idx = threadIdx.x; idx < NV*NV; idx += 256) {
            int c = idx / 16, j = idx % 16;
            float acc = 0.f;
            for (int a = 0; a < 32; ++a) acc += es[a]*Wv[(c*DD + a)*NV + j];
            oV[idx] = acc;
        }
    } else if (b <= 1600) {
        int idx = (b - 65)*256 + threadIdx.x;      // L*64*3072 total, coalesced read
        int l = idx / (HRD*NWW);
        int r = idx - l*(HRD*NWW);
        int k = r / NWW;
        int c = r - k*NWW;
        int ch = c >> 6, cc = c & 63, q = cc >> 4, tcc = cc & 15;
        int h = k >> 5, qd = (k >> 3) & 3, j = k & 7;
        size_t dst = (size_t)l*(NWW*HRD)
                   + (size_t)((ch*32 + q*8 + h*4 + qd)*128 + tcc*8 + j);
        wr2t[dst] = __float2bfloat16(Wr2[idx]);
    } else {
        int i = (b - 1601)*256 + threadIdx.x;
        if (i < NN) { deg[i] = 0; cursor[i] = 0; }
    }
}

// --------------------------------------------------------------- CSR build
__global__ void k_hist(const int* __restrict__ edst, int* __restrict__ deg) {
    int e = blockIdx.x*256 + threadIdx.x;
    atomicAdd(&deg[edst[e]], 1);
}

__global__ void k_scan(const int* __restrict__ deg, int* __restrict__ row_ptr) {
    __shared__ int part[256];
    __shared__ int psc[256];
    int t = threadIdx.x;
    int loc[8]; int s = 0;
    for (int k = 0; k < 8; ++k) { loc[k] = deg[t*8 + k]; s += loc[k]; }
    part[t] = s;
    __syncthreads();
    if (t == 0) { int run = 0; for (int i = 0; i < 256; ++i) { psc[i] = run; run += part[i]; } }
    __syncthreads();
    int off = psc[t];
    for (int k = 0; k < 8; ++k) { row_ptr[t*8 + k] = off; off += loc[k]; }
    if (t == 255) row_ptr[2048] = off;
}

// blocks 0..127: fill invperm + pre-permuted src/dst; blocks 128..135: init y
__global__ void k_fill(const int* __restrict__ esrc, const int* __restrict__ edst,
                       const int* __restrict__ row_ptr, int* __restrict__ cursor,
                       int* __restrict__ invperm, int* __restrict__ srcs, int* __restrict__ dsts,
                       const float* __restrict__ xin, const float* __restrict__ Q,
                       float* __restrict__ ys0, float* __restrict__ yv0,
                       float* __restrict__ ys1, float* __restrict__ yv1,
                       float* __restrict__ xcur) {
    if (blockIdx.x < 128) {
        int e = blockIdx.x*256 + threadIdx.x;
        int d = edst[e];
        int pos = atomicAdd(&cursor[d], 1);
        int p = row_ptr[d] + pos;
        invperm[e] = p;
        srcs[p] = esrc[e];
        dsts[p] = d;
    } else {
        int n = (blockIdx.x - 128)*256 + threadIdx.x;  // exactly 2048
        float xl[6];
        for (int i = 0; i < 6; ++i) { xl[i] = xin[n*6 + i]; xcur[n*6 + i] = xl[i]; }
        for (int j = 0; j < 32; ++j) { ys0[n*32 + j] = 0.f; ys1[n*32 + j] = 0.f; }
        for (int c = 0; c < 16; ++c)
            for (int k = 0; k < 3; ++k) {
                float v = Q[c*2 + 0]*xl[k] + Q[c*2 + 1]*xl[3 + k];
                yv0[n*48 + c*3 + k] = v;
                yv1[n*48 + c*3 + k] = v;
            }
    }
}

// -------------------- K_pre: blocks 0..127 edge geometry+radial1 (permuted
// write), blocks 128..511 node lin1 + aggregator zeroing
__global__ void __launch_bounds__(256) k_pre(
        const float* __restrict__ xcur,
        const int* __restrict__ esrc, const int* __restrict__ edst,
        const int* __restrict__ invperm,
        const float* __restrict__ Wr1l,
        __hip_bfloat16* __restrict__ hrg, float* __restrict__ eag,
        const float* __restrict__ ys, const float* __restrict__ yv,
        const float* __restrict__ Wl1s, const float* __restrict__ Wl1v,
        float* __restrict__ s1, float* __restrict__ v1,
        float* __restrict__ nsb, float* __restrict__ nvba, float* __restrict__ nvbb) {
    if (blockIdx.x < 128) {
        __shared__ float Wr1[16*64];
        for (int i = threadIdx.x; i < 16*64; i += 256) Wr1[i] = Wr1l[i];
        __syncthreads();
        int e = blockIdx.x*256 + threadIdx.x;
        int s = esrc[e], d = edst[e];
        int p = invperm[e];
        float ef[16];
        for (int m = 0; m < 2; ++m) {
            float v0 = xcur[s*6 + m*3 + 0] - xcur[d*6 + m*3 + 0];
            float v1_ = xcur[s*6 + m*3 + 1] - xcur[d*6 + m*3 + 1];
            float v2 = xcur[s*6 + m*3 + 2] - xcur[d*6 + m*3 + 2];
            float len = sqrtf(v0*v0 + v1_*v1_ + v2*v2 + 1e-12f);
            float inv = 1.0f/len;
            float theta = len*(PI_F/3.0f);
            float s1v = sinf(theta), c1v = cosf(theta);
            float sc  = 2.3094010767585034f*inv;  // sqrt(2/3)*sqrt(8)
            float sp = 0.f, scur = s1v, twoc = 2.f*c1v;
            for (int bq = 0; bq < 8; ++bq) {
                ef[m*8 + bq] = sc*scur;
                float sn = twoc*scur - sp;
                sp = scur; scur = sn;
            }
            float u = 2.0f*(len*(1.0f/3.0f) - 1.0f);
            float cut;
            if (u > 0.f) cut = 0.f;
            else if (u < -1.f) cut = 1.f;
            else cut = 0.5f*(1.0f - cosf(PI_F*u));
            float shs = 1.7320508075688772f*inv*cut;
            eag[p*6 + m*3 + 0] = shs*v0;
            eag[p*6 + m*3 + 1] = shs*v1_;
            eag[p*6 + m*3 + 2] = shs*v2;
        }
        for (int hh = 0; hh < 64; ++hh) {
            float z = 0.f;
            for (int f = 0; f < 16; ++f) z += ef[f]*Wr1[f*64 + hh];
            z *= SC_R1;
            hrg[(size_t)p*64 + hh] = __float2bfloat16(z/(1.0f + expf(-z)));
        }
    } else {
        int idx = (blockIdx.x - 128)*256 + threadIdx.x;  // exactly 2048*48
        int n = idx / 48, r = idx % 48;
        nsb[idx] = 0.f;
        nvba[idx] = 0.f;
        nvbb[idx] = 0.f;
        if (r < 32) {
            float acc = 0.f;
            for (int i = 0; i < 32; ++i) acc += ys[n*32 + i]*Wl1s[i*32 + r];
            s1[n*32 + r] = acc*SC_L1S;
        }
        int j = r/3, k = r - 3*j;
        float acc = 0.f;
        for (int c = 0; c < 16; ++c) acc += yv[n*48 + c*3 + k]*Wl1v[c*16 + j];
        v1[idx] = acc*SC_L1V;
    }
}

// ------------------------------ K_tp: fused radial2-MFMA + edge TP + reduce
// 128 edges/block, 3 region-blocks per tile (bid%3: 0=sv,1=vs,2=vv).
// B staged into LDS once per block per chunk via global_load_lds (double-
// buffered, 1 barrier/chunk) -> ~8x fewer per-CU vmem line-requests than
// per-wave global B loads. Each wave owns 2 MFMA row-tiles. Dst-sorted
// exclusive-store reduction unchanged.
__global__ void __launch_bounds__(256, 3) k_tp(
        const __hip_bfloat16* __restrict__ hrg, const float* __restrict__ eag,
        const float* __restrict__ s1g, const float* __restrict__ v1g,
        const int* __restrict__ srcs, const int* __restrict__ dsts,
        const int* __restrict__ row_ptr,
        const __hip_bfloat16* __restrict__ wr2tl,
        float* __restrict__ nsb, float* __restrict__ nvba, float* __restrict__ nvbb) {
    __shared__ __align__(16) char smem[42240];
    __shared__ float ea_s[TPE][8];
    __shared__ int   src_s[TPE];
    __shared__ int   dst_s[TPE];

    int bid = blockIdx.x;
    int region = bid % 3;
    int tile   = bid / 3;
    int ebase  = tile*TPE;
    int tid = threadIdx.x;
    int wave = tid >> 6, lane = tid & 63;
    int tc = tid & 15;
    int quad = lane >> 4;

    if (tid < TPE) { src_s[tid] = srcs[ebase + tid]; dst_s[tid] = dsts[ebase + tid]; }
    for (int i = tid; i < TPE*6; i += 256) ea_s[i/6][i%6] = eag[(size_t)ebase*6 + i];
    __syncthreads();

    // A fragments: 2 row-tiles per wave (chunk-invariant)
    const short* hr16 = (const short*)hrg;
    short8 a_lo[2], a_hi[2];
    #pragma unroll
    for (int rt = 0; rt < 2; ++rt) {
        int arow = ebase + (wave*2 + rt)*16 + tc;
        a_lo[rt] = *(const short8*)(hr16 + (size_t)arow*64 + quad*8);
        a_hi[rt] = *(const short8*)(hr16 + (size_t)arow*64 + 32 + quad*8);
    }

    const char* wb = (const char*)wr2tl;   // staging layout: chunk ch at ch*8192
    const float sES = SC_R2*SC_ES*SC_AGG;
    const float sEV = SC_R2*SC_EV*SC_AGG;

    char* Bbuf;
    if (region == 0)      Bbuf = smem + 16896;
    else if (region == 1) Bbuf = smem + 16896;
    else                  Bbuf = smem + 25344;

    auto stage = [&](int ch, int b) {
        const char* g = wb + (size_t)ch*8192 + wave*2048 + lane*16;
        char* l = Bbuf + b*8192 + wave*2048;       // wave-uniform lds base
        load_lds16(g, l);
        load_lds16(g + 1024, l + 1024);
    };

    if (region == 0) {
        // ---------------- sv: ch 0..15 -> accEV -> nvb_a
        float (*s1t)[132] = (float(*)[132])smem;            // 16896 B
        for (int i = tid; i < TPE*32; i += 256) {
            int e = i >> 5, s = i & 31;
            s1t[s][e] = s1g[src_s[e]*32 + s];
        }
        stage(0, 0);

        float accEV[2][4][3] = {};
        for (int ci = 0; ci < 16; ++ci) {
            __syncthreads();                       // drains stage(ci) + gather
            if (ci + 1 < 16) stage(ci + 1, (ci + 1) & 1);
            const char* B = Bbuf + (ci & 1)*8192;
            #pragma unroll
            for (int q = 0; q < 4; ++q) {
                short8 b_lo = *(const short8*)(B + (q*8 + quad)*256 + tc*16);
                short8 b_hi = *(const short8*)(B + (q*8 + 4 + quad)*256 + tc*16);
                floatx4 c0 = {0.f,0.f,0.f,0.f}, c1 = {0.f,0.f,0.f,0.f};
                c0 = mfma16(a_lo[0], b_lo, c0); c0 = mfma16(a_hi[0], b_hi, c0);
                c1 = mfma16(a_lo[1], b_lo, c1); c1 = mfma16(a_hi[1], b_hi, c1);
                int m = q & 1;
                int sidx = ci*2 + (q >> 1);
                #pragma unroll
                for (int rt = 0; rt < 2; ++rt) {
                    int e0r = (wave*2 + rt)*16 + quad*4;
                    float4 sv = *(const float4*)&s1t[sidx][e0r];
                    floatx4 cc = rt ? c1 : c0;
                    #pragma unroll
                    for (int i = 0; i < 4; ++i) {
                        float f = cc[i]*((&sv.x)[i]);
                        accEV[rt][i][0] += f*ea_s[e0r + i][m*3 + 0];
                        accEV[rt][i][1] += f*ea_s[e0r + i][m*3 + 1];
                        accEV[rt][i][2] += f*ea_s[e0r + i][m*3 + 2];
                    }
                }
            }
        }
        __syncthreads();
        float (*red)[49] = (float(*)[49])smem;
        #pragma unroll
        for (int rt = 0; rt < 2; ++rt) {
            int e0r = (wave*2 + rt)*16 + quad*4;
            #pragma unroll
            for (int i = 0; i < 4; ++i) {
                int pos = e0r + i;
                red[pos][tc*3 + 0] = accEV[rt][i][0]*sEV;
                red[pos][tc*3 + 1] = accEV[rt][i][1]*sEV;
                red[pos][tc*3 + 2] = accEV[rt][i][2]*sEV;
            }
        }
        __syncthreads();
        if (tid < 48) {
            int c = tid;
            float run = 0.f;
            int cur = dst_s[0];
            for (int pos = 0; pos < TPE; ++pos) {
                int d = dst_s[pos];
                if (d != cur) {
                    if (row_ptr[cur] >= ebase && row_ptr[cur + 1] <= ebase + TPE)
                        nvba[cur*48 + c] = run;
                    else
                        atomicAdd(&nvba[cur*48 + c], run);
                    run = 0.f; cur = d;
                }
                run += red[pos][c];
            }
            if (row_ptr[cur] >= ebase && row_ptr[cur + 1] <= ebase + TPE)
                nvba[cur*48 + c] = run;
            else
                atomicAdd(&nvba[cur*48 + c], run);
        }
    } else if (region == 1) {
        // ---------------- vs: ch 16..39 -> accES -> nsb
        float (*dots_t)[132] = (float(*)[132])smem;           // 16896 B
        float (*v1t)[132]    = (float(*)[132])(smem + 16896); // 25344 B (dies)
        for (int i = tid; i < TPE*48; i += 256) {
            int e = i/48, j = i%48;
            v1t[j][e] = v1g[src_s[e]*48 + j];
        }
        __syncthreads();
        for (int i = tid; i < TPE*32; i += 256) {
            int cm = i >> 7, e = i & (TPE - 1), c = cm >> 1, m = cm & 1;
            dots_t[cm][e] = v1t[c*3+0][e]*ea_s[e][m*3+0]
                          + v1t[c*3+1][e]*ea_s[e][m*3+1]
                          + v1t[c*3+2][e]*ea_s[e][m*3+2];
        }
        __syncthreads();   // v1t dead; Bbuf may now overwrite it
        stage(16, 0);

        float accES[2][4][3] = {};
        for (int ci = 16; ci < 40; ++ci) {
            __syncthreads();
            if (ci + 1 < 40) stage(ci + 1, (ci + 1) & 1);
            const char* B = Bbuf + (ci & 1)*8192;
            #pragma unroll
            for (int q = 0; q < 4; ++q) {
                short8 b_lo = *(const short8*)(B + (q*8 + quad)*256 + tc*16);
                short8 b_hi = *(const short8*)(B + (q*8 + 4 + quad)*256 + tc*16);
                floatx4 c0 = {0.f,0.f,0.f,0.f}, c1 = {0.f,0.f,0.f,0.f};
                c0 = mfma16(a_lo[0], b_lo, c0); c0 = mfma16(a_hi[0], b_hi, c0);
                c1 = mfma16(a_lo[1], b_lo, c1); c1 = mfma16(a_hi[1], b_hi, c1);
                int u = ci*4 + q - 64;           // [0,96)
                int c = (u*10923) >> 16;         // u/6
                int v6 = u - 6*c;
                int m = (v6 >= 3) ? 1 : 0;
                int g = v6 - 3*m;
                #pragma unroll
                for (int rt = 0; rt < 2; ++rt) {
                    int e0r = (wave*2 + rt)*16 + quad*4;
                    float4 dv = *(const float4*)&dots_t[c*2 + m][e0r];
                    floatx4 cc = rt ? c1 : c0;
                    #pragma unroll
                    for (int i = 0; i < 4; ++i)
                        accES[rt][i][g] += cc[i]*((&dv.x)[i]);
                }
            }
        }
        __syncthreads();
        float (*red)[49] = (float(*)[49])smem;
        #pragma unroll
        for (int rt = 0; rt < 2; ++rt) {
            int e0r = (wave*2 + rt)*16 + quad*4;
            #pragma unroll
            for (int i = 0; i < 4; ++i) {
                int pos = e0r + i;
                red[pos][tc]      = accES[rt][i][0]*sES;
                red[pos][16 + tc] = accES[rt][i][1]*sES;
                red[pos][32 + tc] = accES[rt][i][2]*sES;
            }
        }
        __syncthreads();
        if (tid < 48) {
            int c = tid;
            float run = 0.f;
            int cur = dst_s[0];
            for (int pos = 0; pos < TPE; ++pos) {
                int d = dst_s[pos];
                if (d != cur) {
                    if (row_ptr[cur] >= ebase && row_ptr[cur + 1] <= ebase + TPE)
                        nsb[cur*48 + c] = run;
                    else
                        atomicAdd(&nsb[cur*48 + c], run);
                    run = 0.f; cur = d;
                }
                run += red[pos][c];
            }
            if (row_ptr[cur] >= ebase && row_ptr[cur + 1] <= ebase + TPE)
                nsb[cur*48 + c] = run;
            else
                atomicAdd(&nsb[cur*48 + c], run);
        }
    } else {
        // ---------------- vv: ch 40..47 -> accEV (cross) -> nvb_b
        float (*v1t)[132] = (float(*)[132])smem;              // 25344 B
        for (int i = tid; i < TPE*48; i += 256) {
            int e = i/48, j = i%48;
            v1t[j][e] = v1g[src_s[e]*48 + j];
        }
        stage(40, 0);   // Bbuf disjoint from v1t

        float accEV[2][4][3] = {};
        for (int ci = 40; ci < 48; ++ci) {
            __syncthreads();
            if (ci + 1 < 48) stage(ci + 1, (ci + 1) & 1);
            const char* B = Bbuf + (ci & 1)*8192;
            #pragma unroll
            for (int q = 0; q < 4; ++q) {
                short8 b_lo = *(const short8*)(B + (q*8 + quad)*256 + tc*16);
                short8 b_hi = *(const short8*)(B + (q*8 + 4 + quad)*256 + tc*16);
                floatx4 c0 = {0.f,0.f,0.f,0.f}, c1 = {0.f,0.f,0.f,0.f};
                c0 = mfma16(a_lo[0], b_lo, c0); c0 = mfma16(a_hi[0], b_hi, c0);
                c1 = mfma16(a_lo[1], b_lo, c1); c1 = mfma16(a_hi[1], b_hi, c1);
                int c = ci*2 - 80 + (q >> 1);
                int m = q & 1;
                #pragma unroll
                for (int rt = 0; rt < 2; ++rt) {
                    int e0r = (wave*2 + rt)*16 + quad*4;
                    float4 vx = *(const float4*)&v1t[c*3 + 0][e0r];
                    float4 vy = *(const float4*)&v1t[c*3 + 1][e0r];
                    float4 vz = *(const float4*)&v1t[c*3 + 2][e0r];
                    floatx4 cc = rt ? c1 : c0;
                    #pragma unroll
                    for (int i = 0; i < 4; ++i) {
                        float ww = cc[i];
                        float a0 = ea_s[e0r + i][m*3 + 0];
                        float a1 = ea_s[e0r + i][m*3 + 1];
                        float a2 = ea_s[e0r + i][m*3 + 2];
                        float xv = (&vx.x)[i], yv = (&vy.x)[i], zv = (&vz.x)[i];
                        accEV[rt][i][0] += ww*(yv*a2 - zv*a1);
                        accEV[rt][i][1] += ww*(zv*a0 - xv*a2);
                        accEV[rt][i][2] += ww*(xv*a1 - yv*a0);
                    }
                }
            }
        }
        __syncthreads();
        float (*red)[49] = (float(*)[49])smem;
        #pragma unroll
        for (int rt = 0; rt < 2; ++rt) {
            int e0r = (wave*2 + rt)*16 + quad*4;
            #pragma unroll
            for (int i = 0; i < 4; ++i) {
                int pos = e0r + i;
                red[pos][tc*3 + 0] = accEV[rt][i][0]*sEV;
                red[pos][tc*3 + 1] = accEV[rt][i][1]*sEV;
                red[pos][tc*3 + 2] = accEV[rt][i][2]*sEV;
            }
        }
        __syncthreads();
        if (tid < 48) {
            int c = tid;
            float run = 0.f;
            int cur = dst_s[0];
            for (int pos = 0; pos < TPE; ++pos) {
                int d = dst_s[pos];
                if (d != cur) {
                    if (row_ptr[cur] >= ebase && row_ptr[cur + 1] <= ebase + TPE)
                        nvbb[cur*48 + c] = run;
                    else
                        atomicAdd(&nvbb[cur*48 + c], run);
                    run = 0.f; cur = d;
                }
                run += red[pos][c];
            }
            if (row_ptr[cur] >= ebase && row_ptr[cur + 1] <= ebase + TPE)
                nvbb[cur*48 + c] = run;
            else
                atomicAdd(&nvbb[cur*48 + c], run);
        }
    }
}

// ----------------------- K6: node update (conv, gate, si, leapfrog, project)
__global__ void __launch_bounds__(256) k_nodepost(
        const float* __restrict__ ysC, const float* __restrict__ yvC,
        float* __restrict__ ysO, float* __restrict__ yvO,
        const float* __restrict__ nsb, const float* __restrict__ nvba,
        const float* __restrict__ nvbb,
        const int* __restrict__ nattr,
        const float* __restrict__ WtSl, const float* __restrict__ WtVl,
        const float* __restrict__ Wl2s, const float* __restrict__ Wl2v,
        const float* __restrict__ Wsis, const float* __restrict__ Wsiv,
        const float* __restrict__ harr, const float* __restrict__ mixarr, int l,
        float* __restrict__ xcur, float* __restrict__ xout2,
        const float* __restrict__ Qg) {
    int wave = threadIdx.x >> 6, lane = threadIdx.x & 63;
    int n = blockIdx.x*4 + wave;
    __shared__ float ys_s[4][32], yv_s[4][48], ns_s[4][48], nv_s[4][48];
    __shared__ float cs_s[4][48], nvo_s[4][48];

    if (lane < 32) ys_s[wave][lane] = ysC[n*32 + lane];
    if (lane < 48) {
        yv_s[wave][lane] = yvC[n*48 + lane];
        ns_s[wave][lane] = nsb[n*48 + lane];
        nv_s[wave][lane] = nvba[n*48 + lane] + nvbb[n*48 + lane];
    }
    __syncthreads();
    int t = nattr[n];
    const float* WtSn = WtSl + (size_t)t*NS*48;
    const float* WtVn = WtVl + (size_t)t*NV*NV;
    float hv = harr[l];
    float h2 = hv*hv, mx = mixarr[l];

    if (lane < 48) {
        float sc = 0.f, s2 = 0.f;
        for (int i = 0; i < 32; ++i) sc += ys_s[wave][i]*WtSn[i*48 + lane];
        for (int c = 0; c < 48; ++c) s2 += ns_s[wave][c]*Wl2s[c*48 + lane];
        cs_s[wave][lane] = sc*SC_SCS + s2*SC_L2S;
    }
    __syncthreads();
    if (lane < 48) {
        int j = lane/3, k = lane - 3*j;
        float scv = 0.f, v2 = 0.f, siv = 0.f;
        for (int c = 0; c < 16; ++c) {
            float yvv = yv_s[wave][c*3 + k];
            scv += yvv*WtVn[c*16 + j];
            v2  += nv_s[wave][c*3 + k]*Wl2v[c*16 + j];
            siv += yvv*Wsiv[c*16 + j];
        }
        float convv = scv*SC_SCV + v2*SC_L2V;
        siv *= SC_SIV;
        float gate = 1.f/(1.f + expf(-cs_s[wave][32 + j]));
        float gv = gate*convv;
        float nvnew = 2.f*yv_s[wave][lane] - yvO[n*48 + lane] + h2*(mx*gv + (mx - 1.f)*siv);
        nvo_s[wave][lane] = nvnew;
        yvO[n*48 + lane] = nvnew;
    }
    if (lane < 32) {
        float sis = 0.f;
        for (int i = 0; i < 32; ++i) sis += ys_s[wave][i]*Wsis[i*32 + lane];
        sis *= SC_SIS;
        float cs = cs_s[wave][lane];
        float gs = cs/(1.f + expf(-cs));
        float nsnew = 2.f*ys_s[wave][lane] - ysO[n*32 + lane] + h2*(mx*gs + (mx - 1.f)*sis);
        ysO[n*32 + lane] = nsnew;
    }
    __syncthreads();
    if (lane < 6) {
        int i = lane/3, k = lane - 3*(lane/3);
        float acc = 0.f;
        for (int c = 0; c < 16; ++c) acc += Qg[c*2 + i]*nvo_s[wave][c*3 + k];
        xcur[n*6 + lane]  = acc;
        xout2[n*6 + lane] = acc;
    }
}

// ---------------------------------------------------------------- launch
extern "C" void kernel_launch(void* const* d_in, const int* in_sizes, int n_in,
                              void* d_out, int out_size, void* d_ws, size_t ws_size,
                              hipStream_t stream) {
    const float* x_in  = (const float*)d_in[0];
    const int*   nattr = (const int*)  d_in[2];
    const int*   esrc  = (const int*)  d_in[3];
    const int*   edst  = (const int*)  d_in[4];
    const float* emb   = (const float*)d_in[5];
    const float* Wup   = (const float*)d_in[6];
    const float* Wscs  = (const float*)d_in[7];
    const float* Wscv  = (const float*)d_in[8];
    const float* Wl1s  = (const float*)d_in[9];
    const float* Wl1v  = (const float*)d_in[10];
    const float* Wr1   = (const float*)d_in[11];
    const float* Wr2   = (const float*)d_in[12];
    const float* Wl2s  = (const float*)d_in[13];
    const float* Wl2v  = (const float*)d_in[14];
    const float* Wsis  = (const float*)d_in[15];
    const float* Wsiv  = (const float*)d_in[16];
    const float* harr  = (const float*)d_in[17];
    const float* mixar = (const float*)d_in[18];
    float* out = (float*)d_out;

    float* ws = (float*)d_ws;
    size_t off = 0;
    float* Q    = ws + off; off += 32;
    float* WtS  = ws + off; off += (size_t)LL*TT*NS*48;     // 98304
    float* WtV  = ws + off; off += (size_t)LL*TT*NV*NV;     // 16384
    float* ys0  = ws + off; off += (size_t)NN*32;
    float* yv0  = ws + off; off += (size_t)NN*48;
    float* ys1  = ws + off; off += (size_t)NN*32;
    float* yv1  = ws + off; off += (size_t)NN*48;
    float* xcur = ws + off; off += (size_t)NN*6;
    float* s1   = ws + off; off += (size_t)NN*32;
    float* v1   = ws + off; off += (size_t)NN*48;
    float* nsb  = ws + off; off += (size_t)NN*48;
    float* nvba = ws + off; off += (size_t)NN*48;
    float* nvbb = ws + off; off += (size_t)NN*48;
    float* eab  = ws + off; off += (size_t)EE*6;
    off = (off + 3) & ~(size_t)3;                           // 16B align
    __hip_bfloat16* hrb  = (__hip_bfloat16*)(ws + off); off += (size_t)EE*64/2;       // bf16
    __hip_bfloat16* wr2t = (__hip_bfloat16*)(ws + off); off += (size_t)LL*NWW*HRD/2;  // bf16
    int* deg     = (int*)(ws + off); off += NN;
    int* cursor  = (int*)(ws + off); off += NN;
    int* row_ptr = (int*)(ws + off); off += NN + 1;
    int* invperm = (int*)(ws + off); off += EE;
    int* srcs    = (int*)(ws + off); off += EE;
    int* dsts    = (int*)(ws + off); off += EE;

    k_setup<<<1609, 256, 0, stream>>>(Wup, Q, emb, Wscs, Wscv, WtS, WtV, Wr2, wr2t,
                                      deg, cursor);
    k_hist<<<EE/256, 256, 0, stream>>>(edst, deg);
    k_scan<<<1, 256, 0, stream>>>(deg, row_ptr);
    k_fill<<<136, 256, 0, stream>>>(esrc, edst, row_ptr, cursor, invperm, srcs, dsts,
                                    x_in, Q, ys0, yv0, ys1, yv1, xcur);

    float* curS = ys0; float* curV = yv0;
    float* oldS = ys1; float* oldV = yv1;
    for (int l = 0; l < LL; ++l) {
        k_pre<<<512, 256, 0, stream>>>(xcur, esrc, edst, invperm,
                                       Wr1 + (size_t)l*16*64, hrb, eab,
                                       curS, curV, Wl1s + (size_t)l*32*32,
                                       Wl1v + (size_t)l*16*16, s1, v1, nsb, nvba, nvbb);
        k_tp<<<3*EE/TPE, 256, 0, stream>>>(hrb, eab, s1, v1, srcs, dsts, row_ptr,
                                           wr2t + (size_t)l*NWW*HRD, nsb, nvba, nvbb);
        float* xo2 = (l == LL - 1) ? out : xcur;
        k_nodepost<<<NN/4, 256, 0, stream>>>(curS, curV, oldS, oldV, nsb, nvba, nvbb, nattr,
                                             WtS + (size_t)l*TT*NS*48, WtV + (size_t)l*TT*NV*NV,
                                             Wl2s + (size_t)l*48*48, Wl2v + (size_t)l*16*16,
                                             Wsis + (size_t)l*32*32, Wsiv + (size_t)l*16*16,
                                             harr, mixar, l, xcur, xo2, Q);
        float* ts = curS; curS = oldS; oldS = ts;
        float* tv = curV; curV = oldV; oldV = tv;
    }
}